// Round 1
// baseline (635.116 us; speedup 1.0000x reference)
//
#include <hip/hip_runtime.h>
#include <stdint.h>
#include <stddef.h>

// SinkhornScorer fused kernel for MI355X (gfx950).
// One workgroup (256 threads) per batch element b:
//   phase 1: stream x_b,y_b (36x768 fp32) once: fp32 row stats + bf16 LDS tiles
//   phase 2: MFMA 16x16x32 bf16 -> raw dot products, scaled by 1/(|x||y|)
//   phase 3: wave (b&3) Sinkhorn (20 iters) in base-2 log domain
//            (block-dependent wave spreads the serial phase across all 4 SIMDs)
//   phase 4: Z write + <P,S> block reduction
// LDS: A/B tiles clamped to 36 rows (MFMA frag rows >=36 clamp to 35; their
// outputs are discarded anyway), C2T aliased into the dead A/B tile space
// -> ~27.6 KB/block -> 5 blocks/CU residency.

typedef float  f4  __attribute__((ext_vector_type(4)));
typedef short  s8v __attribute__((ext_vector_type(8)));
typedef unsigned int u2v __attribute__((ext_vector_type(2)));

#define HD   768
#define MR   36          // rows (M == N == 36)
#define KC   128         // K-chunk
#define NCH  6           // 768/128
#define AS   136         // LDS row stride (bf16 elems) for A/B tiles
#define CS   44          // LDS row stride (floats) for C2/C2T
#define ITERS 20
#define LOG2E 1.4426950408889634f
#define LN2   0.6931471805599453f
#define L272  6.169925001442312f   // log2(72) = -norm_c in base-2
#define KC2   (10.0f*LOG2E)        // couplings scale: /REG then *log2e
#define NEGB  (-1.0e30f)

__device__ __forceinline__ uint32_t pkbf2(float a, float b) {
    // two fp32 -> packed bf16 (RNE)
    uint32_t ua = __float_as_uint(a), ub = __float_as_uint(b);
    ua += 0x7FFFu + ((ua >> 16) & 1u);
    ub += 0x7FFFu + ((ub >> 16) & 1u);
    return (ua >> 16) | (ub & 0xFFFF0000u);
}

__device__ __forceinline__ f4 fmax4(f4 a, f4 b) {
    f4 r;
    r.x = fmaxf(a.x, b.x); r.y = fmaxf(a.y, b.y);
    r.z = fmaxf(a.z, b.z); r.w = fmaxf(a.w, b.w);
    return r;
}

__global__ __launch_bounds__(256, 5) void sinkhorn_kernel(
    const float* __restrict__ X, const float* __restrict__ Y,
    const float* __restrict__ LG, const float* __restrict__ LB,
    const float* __restrict__ W,  const float* __restrict__ BL,
    float* __restrict__ OUT, int NB)
{
    // A tile rows 0..35, B tile rows 0..35 (frag rows >=36 clamped).
    __shared__ __align__(16) uint16_t AB[72 * AS];   // phase 1/2; later reused as C2T
    __shared__ __align__(16) float C2 [37 * CS];     // couplings * log2e, cols 37..39 = -1e30 pad
    __shared__ __align__(16) float u_l[40];
    __shared__ __align__(16) float v_l[40];
    __shared__ float stx[MR * 3], sty[MR * 3];       // per-row {Sx, Sxx, Sxw}
    __shared__ float rnx[MR], rny[MR];               // 1/||row||
    __shared__ float s_gw, s_bw, red[4];

    uint16_t* Al = AB;
    uint16_t* Bt = AB + 36 * AS;
    float*    C2T = (float*)AB;                      // valid only after MFMA phase

    const int t  = threadIdx.x;
    const int b  = blockIdx.x;
    const int wv = t >> 6, ln = t & 63;
    const int c4 = t & 31, gg = t >> 5;

    // ---- one-time inits (no barrier needed before first chunk barrier) ----
    if (t < 40) { u_l[t] = 0.0f; v_l[t] = 0.0f; }
    if (t < 37) {
        C2[t * CS + 37] = NEGB; C2[t * CS + 38] = NEGB; C2[t * CS + 39] = NEGB;
    }
    if (wv == 3) {  // Sgw = sum g*w, Sbw = sum b*w (wave 3, once)
        float a = 0.0f, c = 0.0f;
        for (int q = 0; q < 12; ++q) {
            int h = ln + 64 * q;
            float wval = W[h];
            a += LG[h] * wval; c += LB[h] * wval;
        }
        for (int o = 32; o > 0; o >>= 1) { a += __shfl_down(a, o); c += __shfl_down(c, o); }
        if (ln == 0) { s_gw = a; s_bw = c; }
    }

    float sx[5][3], sy[5][3];
    #pragma unroll
    for (int p = 0; p < 5; ++p)
        #pragma unroll
        for (int s = 0; s < 3; ++s) { sx[p][s] = 0.0f; sy[p][s] = 0.0f; }

    f4 acc[3];
    #pragma unroll
    for (int i = 0; i < 3; ++i) acc[i] = (f4){0.0f, 0.0f, 0.0f, 0.0f};

    const float* xb = X + (size_t)b * (MR * HD);
    const float* yb = Y + (size_t)b * (MR * HD);

    const int frow = ln & 15, fq = ln >> 4;          // MFMA fragment row / k-quad
    // clamped fragment bases: rows >=36 read row 35 (their outputs are discarded)
    const int arR = wv * 16 + frow;
    const int rA  = ((arR < MR) ? arR : (MR - 1)) * AS + fq * 8;   // waves 0..2
    const int rB0 = (frow)      * AS + fq * 8;
    const int rB1 = (16 + frow) * AS + fq * 8;
    const int bt2 = 32 + frow;
    const int rB2 = ((bt2 < MR) ? bt2 : (MR - 1)) * AS + fq * 8;

    // ---- phase 1+2: staged K-loop ----
    for (int kc = 0; kc < NCH; ++kc) {
        const int k0 = kc * KC;
        f4 gv = *(const f4*)(LG + k0 + c4 * 4);
        f4 wvec = *(const f4*)(W + k0 + c4 * 4);
        f4 gw = gv * wvec;
        #pragma unroll
        for (int p = 0; p < 5; ++p) {
            if (p < 4 || t < 128) {
                const int row = (p < 4) ? (p * 8 + gg) : (32 + gg);
                f4 xv = *(const f4*)(xb + row * HD + k0 + c4 * 4);
                sx[p][0] += (xv.x + xv.y) + (xv.z + xv.w);
                sx[p][1] += xv.x * xv.x + xv.y * xv.y + xv.z * xv.z + xv.w * xv.w;
                sx[p][2] += xv.x * gw.x + xv.y * gw.y + xv.z * gw.z + xv.w * gw.w;
                u2v px; px.x = pkbf2(xv.x, xv.y); px.y = pkbf2(xv.z, xv.w);
                *(u2v*)&Al[row * AS + c4 * 4] = px;
                f4 yv = *(const f4*)(yb + row * HD + k0 + c4 * 4);
                sy[p][0] += (yv.x + yv.y) + (yv.z + yv.w);
                sy[p][1] += yv.x * yv.x + yv.y * yv.y + yv.z * yv.z + yv.w * yv.w;
                sy[p][2] += yv.x * gw.x + yv.y * gw.y + yv.z * gw.z + yv.w * gw.w;
                u2v py; py.x = pkbf2(yv.x, yv.y); py.y = pkbf2(yv.z, yv.w);
                *(u2v*)&Bt[row * AS + c4 * 4] = py;
            }
        }
        __syncthreads();
        if (wv < 3) {
            #pragma unroll
            for (int ks = 0; ks < 4; ++ks) {
                s8v af = *(const s8v*)&Al[rA + ks * 32];
                s8v b0 = *(const s8v*)&Bt[rB0 + ks * 32];
                acc[0] = __builtin_amdgcn_mfma_f32_16x16x32_bf16(af, b0, acc[0], 0, 0, 0);
                s8v b1 = *(const s8v*)&Bt[rB1 + ks * 32];
                acc[1] = __builtin_amdgcn_mfma_f32_16x16x32_bf16(af, b1, acc[1], 0, 0, 0);
                s8v b2 = *(const s8v*)&Bt[rB2 + ks * 32];
                acc[2] = __builtin_amdgcn_mfma_f32_16x16x32_bf16(af, b2, acc[2], 0, 0, 0);
            }
        }
        __syncthreads();
    }

    // ---- stats reduction: 32-lane groups own fixed rows ----
    #pragma unroll
    for (int p = 0; p < 5; ++p) {
        const int row = (p < 4) ? (p * 8 + gg) : (32 + gg);
        #pragma unroll
        for (int s = 0; s < 3; ++s) {
            float a = sx[p][s], c = sy[p][s];
            for (int o = 16; o > 0; o >>= 1) { a += __shfl_down(a, o, 32); c += __shfl_down(c, o, 32); }
            if ((t & 31) == 0 && row < MR) { stx[row * 3 + s] = a; sty[row * 3 + s] = c; }
        }
    }
    __syncthreads();

    // ---- derived per-row: 1/norm, dustbin scores (LayerNorm -> linear -> tanh) ----
    // (A/B tiles are dead now; C2T becomes live here.)
    {
        const float blin = BL[0];
        if (t < MR) {
            float Sx = stx[t * 3], Sxx = stx[t * 3 + 1], Sxw = stx[t * 3 + 2];
            rnx[t] = __builtin_amdgcn_rsqf(Sxx);
            float mu  = Sx * (1.0f / HD);
            float var = Sxx * (1.0f / HD) - mu * mu;
            float rsd = __builtin_amdgcn_rsqf(var + 1e-5f);
            float lin = (Sxw - mu * s_gw) * rsd + s_bw + blin;
            float e   = __builtin_amdgcn_exp2f(2.0f * LOG2E * lin);
            float th  = (e - 1.0f) / (e + 1.0f);
            C2 [t * CS + 36] = th * KC2;
            C2T[36 * CS + t] = th * KC2;
        } else if (t >= 64 && t < 64 + MR) {
            int j = t - 64;
            float Sy = sty[j * 3], Syy = sty[j * 3 + 1], Syw = sty[j * 3 + 2];
            rny[j] = __builtin_amdgcn_rsqf(Syy);
            float mu  = Sy * (1.0f / HD);
            float var = Syy * (1.0f / HD) - mu * mu;
            float rsd = __builtin_amdgcn_rsqf(var + 1e-5f);
            float lin = (Syw - mu * s_gw) * rsd + s_bw + blin;
            float e   = __builtin_amdgcn_exp2f(2.0f * LOG2E * lin);
            float th  = (e - 1.0f) / (e + 1.0f);
            C2 [36 * CS + j] = th * KC2;
            C2T[j * CS + 36] = th * KC2;
        } else if (t == 128) {
            C2 [36 * CS + 36] = -100.0f * KC2;   // ALPHA_BOTH/REG in base-2
            C2T[36 * CS + 36] = -100.0f * KC2;
        } else if (t >= 192 && t < 192 + 37) {
            int r = t - 192;                     // C2T pad cols (re-init: aliased space)
            C2T[r * CS + 37] = NEGB; C2T[r * CS + 38] = NEGB; C2T[r * CS + 39] = NEGB;
        }
    }
    __syncthreads();

    // ---- scores -> couplings (base-2) into C2 and C2T ----
    if (wv < 3) {
        #pragma unroll
        for (int tn = 0; tn < 3; ++tn) {
            #pragma unroll
            for (int r = 0; r < 4; ++r) {
                int i = wv * 16 + fq * 4 + r;   // A-operand index (x row)
                int j = tn * 16 + frow;         // B-operand index (y row)
                if (i < MR && j < MR) {
                    float v = acc[tn][r] * rnx[i] * rny[j] * KC2;
                    C2 [i * CS + j] = v;
                    C2T[j * CS + i] = v;
                }
            }
        }
    }
    __syncthreads();

    // ---- Sinkhorn: wave (b&3) -> spreads the serial phase across SIMDs ----
    if (wv == (b & 3) && ln < 37) {
        const int i = ln;
        const float lmu = (i < MR) ? -L272 : -1.0f;  // log2 marginals (mu == nu for M==N)
        const float* Cr = C2  + i * CS;
        const float* Ct = C2T + i * CS;
        for (int it = 0; it < ITERS; ++it) {
            {   // u-update: LSE over columns j of (C + v)
                f4 s[10], ma, mb;
                #pragma unroll
                for (int jj = 0; jj < 10; ++jj) {
                    f4 sv = *(const f4*)(Cr + jj * 4) + *(const f4*)(&v_l[jj * 4]);
                    s[jj] = sv;
                    if (jj == 0) ma = sv;
                    else if (jj == 1) mb = sv;
                    else if (jj & 1) mb = fmax4(mb, sv);
                    else ma = fmax4(ma, sv);
                }
                f4 mm = fmax4(ma, mb);
                float m = fmaxf(fmaxf(mm.x, mm.y), fmaxf(mm.z, mm.w));
                f4 ea = (f4){0.0f,0.0f,0.0f,0.0f}, eb = (f4){0.0f,0.0f,0.0f,0.0f};
                #pragma unroll
                for (int jj = 0; jj < 10; ++jj) {
                    f4 sv = s[jj], ev;
                    ev.x = __builtin_amdgcn_exp2f(sv.x - m);
                    ev.y = __builtin_amdgcn_exp2f(sv.y - m);
                    ev.z = __builtin_amdgcn_exp2f(sv.z - m);
                    ev.w = __builtin_amdgcn_exp2f(sv.w - m);
                    if (jj & 1) eb += ev; else ea += ev;
                }
                f4 et = ea + eb;
                float ss = (et.x + et.y) + (et.z + et.w);
                u_l[i] = lmu - (m + __builtin_amdgcn_logf(ss));
            }
            {   // v-update: LSE over rows i of (C + u) == over cols of C^T
                f4 s[10], ma, mb;
                #pragma unroll
                for (int jj = 0; jj < 10; ++jj) {
                    f4 sv = *(const f4*)(Ct + jj * 4) + *(const f4*)(&u_l[jj * 4]);
                    s[jj] = sv;
                    if (jj == 0) ma = sv;
                    else if (jj == 1) mb = sv;
                    else if (jj & 1) mb = fmax4(mb, sv);
                    else ma = fmax4(ma, sv);
                }
                f4 mm = fmax4(ma, mb);
                float m = fmaxf(fmaxf(mm.x, mm.y), fmaxf(mm.z, mm.w));
                f4 ea = (f4){0.0f,0.0f,0.0f,0.0f}, eb = (f4){0.0f,0.0f,0.0f,0.0f};
                #pragma unroll
                for (int jj = 0; jj < 10; ++jj) {
                    f4 sv = s[jj], ev;
                    ev.x = __builtin_amdgcn_exp2f(sv.x - m);
                    ev.y = __builtin_amdgcn_exp2f(sv.y - m);
                    ev.z = __builtin_amdgcn_exp2f(sv.z - m);
                    ev.w = __builtin_amdgcn_exp2f(sv.w - m);
                    if (jj & 1) eb += ev; else ea += ev;
                }
                f4 et = ea + eb;
                float ss = (et.x + et.y) + (et.z + et.w);
                v_l[i] = lmu - (m + __builtin_amdgcn_logf(ss));
            }
        }
    }
    __syncthreads();

    // ---- epilogue: Z write + total = <exp(Z), scores>/TEMP ----
    float tot = 0.0f;
    const size_t ob = (size_t)b * 1369;
    for (int e = t; e < 1369; e += 256) {
        int i = e / 37, j = e - i * 37;
        float c2v = C2[i * CS + j];
        float z2  = c2v + u_l[i] + v_l[j] + L272;   // - norm_c == + log2(72) in base-2
        OUT[ob + e] = z2 * LN2;
        if (i < MR && j < MR)
            tot += __builtin_amdgcn_exp2f(z2) * (c2v * (0.1f * LN2));  // scores = C2 * REG * ln2
    }
    for (int o = 32; o > 0; o >>= 1) tot += __shfl_down(tot, o);
    if (ln == 0) red[wv] = tot;
    __syncthreads();
    if (t == 0) OUT[(size_t)NB * 1369 + b] = (red[0] + red[1] + red[2] + red[3]) * 10.0f;  // /TEMP
}

extern "C" void kernel_launch(void* const* d_in, const int* in_sizes, int n_in,
                              void* d_out, int out_size, void* d_ws, size_t ws_size,
                              hipStream_t stream) {
    const float* X  = (const float*)d_in[0];
    const float* Y  = (const float*)d_in[1];
    const float* LG = (const float*)d_in[2];
    const float* LB = (const float*)d_in[3];
    const float* W  = (const float*)d_in[4];
    const float* BL = (const float*)d_in[5];
    const int NB = in_sizes[0] / (MR * HD);   // 2048
    hipLaunchKernelGGL(sinkhorn_kernel, dim3(NB), dim3(256), 0, stream,
                       X, Y, LG, LB, W, BL, (float*)d_out, NB);
}

// Round 3
// 504.507 us; speedup vs baseline: 1.2589x; 1.2589x over previous
//
#include <hip/hip_runtime.h>
#include <stdint.h>
#include <stddef.h>

// SinkhornScorer fused kernel for MI355X (gfx950).
// One workgroup (256 threads) per batch element b:
//   phase 1: stream x_b,y_b (36x768 fp32) once: fp32 row stats + bf16 LDS tiles
//   phase 2: MFMA 16x16x32 bf16 -> raw dot products, scaled by 1/(|x||y|)
//   phase 3: wave (b&3) Sinkhorn (20 iters) in base-2 log domain
//            (block-dependent wave spreads the serial phase across all 4 SIMDs)
//   phase 4: Z write + <P,S> block reduction
// LDS: A/B tiles clamped to 36 rows, C2T aliased into dead tile space
// -> 27648 B/block. Occupancy target 4 blocks/CU (launch_bounds(256,4)):
// the 5-block target forced VGPRs <= 48 (HW 64-reg quantum cliff) and spilled
// the Sinkhorn LSE buffers to scratch (+280 MB HBM traffic, round-1 regression).

typedef float  f4  __attribute__((ext_vector_type(4)));
typedef short  s8v __attribute__((ext_vector_type(8)));
typedef unsigned int u2v __attribute__((ext_vector_type(2)));

#define HD   768
#define MR   36          // rows (M == N == 36)
#define KC   128         // K-chunk
#define NCH  6           // 768/128
#define AS   136         // LDS row stride (bf16 elems) for A/B tiles
#define CS   44          // LDS row stride (floats) for C2/C2T
#define ITERS 20
#define LOG2E 1.4426950408889634f
#define LN2   0.6931471805599453f
#define L272  6.169925001442312f   // log2(72) = -norm_c in base-2
#define KC2   (10.0f*LOG2E)        // couplings scale: /REG then *log2e
#define NEGB  (-1.0e30f)

__device__ __forceinline__ uint32_t pkbf2(float a, float b) {
    // two fp32 -> packed bf16 (RNE)
    uint32_t ua = __float_as_uint(a), ub = __float_as_uint(b);
    ua += 0x7FFFu + ((ua >> 16) & 1u);
    ub += 0x7FFFu + ((ub >> 16) & 1u);
    return (ua >> 16) | (ub & 0xFFFF0000u);
}

__device__ __forceinline__ f4 fmax4(f4 a, f4 b) {
    f4 r;
    r.x = fmaxf(a.x, b.x); r.y = fmaxf(a.y, b.y);
    r.z = fmaxf(a.z, b.z); r.w = fmaxf(a.w, b.w);
    return r;
}

__global__ __launch_bounds__(256, 4) void sinkhorn_kernel(
    const float* __restrict__ X, const float* __restrict__ Y,
    const float* __restrict__ LG, const float* __restrict__ LB,
    const float* __restrict__ W,  const float* __restrict__ BL,
    float* __restrict__ OUT, int NB)
{
    // A tile rows 0..35, B tile rows 0..35 (frag rows >=36 clamped).
    __shared__ __align__(16) uint16_t AB[72 * AS];   // phase 1/2; later reused as C2T
    __shared__ __align__(16) float C2 [37 * CS];     // couplings * log2e, cols 37..39 = -1e30 pad
    __shared__ __align__(16) float u_l[40];
    __shared__ __align__(16) float v_l[40];
    __shared__ float stx[MR * 3], sty[MR * 3];       // per-row {Sx, Sxx, Sxw}
    __shared__ float rnx[MR], rny[MR];               // 1/||row||
    __shared__ float s_gw, s_bw, red[4];

    uint16_t* Al = AB;
    uint16_t* Bt = AB + 36 * AS;
    float*    C2T = (float*)AB;                      // valid only after MFMA phase

    const int t  = threadIdx.x;
    const int b  = blockIdx.x;
    const int wv = t >> 6, ln = t & 63;
    const int c4 = t & 31, gg = t >> 5;

    // ---- one-time inits (no barrier needed before first chunk barrier) ----
    if (t < 40) { u_l[t] = 0.0f; v_l[t] = 0.0f; }
    if (t < 37) {
        C2[t * CS + 37] = NEGB; C2[t * CS + 38] = NEGB; C2[t * CS + 39] = NEGB;
    }
    if (wv == 3) {  // Sgw = sum g*w, Sbw = sum b*w (wave 3, once)
        float a = 0.0f, c = 0.0f;
        for (int q = 0; q < 12; ++q) {
            int h = ln + 64 * q;
            float wval = W[h];
            a += LG[h] * wval; c += LB[h] * wval;
        }
        for (int o = 32; o > 0; o >>= 1) { a += __shfl_down(a, o); c += __shfl_down(c, o); }
        if (ln == 0) { s_gw = a; s_bw = c; }
    }

    float sx[5][3], sy[5][3];
    #pragma unroll
    for (int p = 0; p < 5; ++p)
        #pragma unroll
        for (int s = 0; s < 3; ++s) { sx[p][s] = 0.0f; sy[p][s] = 0.0f; }

    f4 acc[3];
    #pragma unroll
    for (int i = 0; i < 3; ++i) acc[i] = (f4){0.0f, 0.0f, 0.0f, 0.0f};

    const float* xb = X + (size_t)b * (MR * HD);
    const float* yb = Y + (size_t)b * (MR * HD);

    const int frow = ln & 15, fq = ln >> 4;          // MFMA fragment row / k-quad
    // clamped fragment bases: rows >=36 read row 35 (their outputs are discarded)
    const int arR = wv * 16 + frow;
    const int rA  = ((arR < MR) ? arR : (MR - 1)) * AS + fq * 8;   // waves 0..2
    const int rB0 = (frow)      * AS + fq * 8;
    const int rB1 = (16 + frow) * AS + fq * 8;
    const int bt2 = 32 + frow;
    const int rB2 = ((bt2 < MR) ? bt2 : (MR - 1)) * AS + fq * 8;

    // ---- phase 1+2: staged K-loop ----
    for (int kc = 0; kc < NCH; ++kc) {
        const int k0 = kc * KC;
        f4 gv = *(const f4*)(LG + k0 + c4 * 4);
        f4 wvec = *(const f4*)(W + k0 + c4 * 4);
        f4 gw = gv * wvec;
        #pragma unroll
        for (int p = 0; p < 5; ++p) {
            if (p < 4 || t < 128) {
                const int row = (p < 4) ? (p * 8 + gg) : (32 + gg);
                f4 xv = *(const f4*)(xb + row * HD + k0 + c4 * 4);
                sx[p][0] += (xv.x + xv.y) + (xv.z + xv.w);
                sx[p][1] += xv.x * xv.x + xv.y * xv.y + xv.z * xv.z + xv.w * xv.w;
                sx[p][2] += xv.x * gw.x + xv.y * gw.y + xv.z * gw.z + xv.w * gw.w;
                u2v px; px.x = pkbf2(xv.x, xv.y); px.y = pkbf2(xv.z, xv.w);
                *(u2v*)&Al[row * AS + c4 * 4] = px;
                f4 yv = *(const f4*)(yb + row * HD + k0 + c4 * 4);
                sy[p][0] += (yv.x + yv.y) + (yv.z + yv.w);
                sy[p][1] += yv.x * yv.x + yv.y * yv.y + yv.z * yv.z + yv.w * yv.w;
                sy[p][2] += yv.x * gw.x + yv.y * gw.y + yv.z * gw.z + yv.w * gw.w;
                u2v py; py.x = pkbf2(yv.x, yv.y); py.y = pkbf2(yv.z, yv.w);
                *(u2v*)&Bt[row * AS + c4 * 4] = py;
            }
        }
        __syncthreads();
        if (wv < 3) {
            #pragma unroll
            for (int ks = 0; ks < 4; ++ks) {
                s8v af = *(const s8v*)&Al[rA + ks * 32];
                s8v b0 = *(const s8v*)&Bt[rB0 + ks * 32];
                acc[0] = __builtin_amdgcn_mfma_f32_16x16x32_bf16(af, b0, acc[0], 0, 0, 0);
                s8v b1 = *(const s8v*)&Bt[rB1 + ks * 32];
                acc[1] = __builtin_amdgcn_mfma_f32_16x16x32_bf16(af, b1, acc[1], 0, 0, 0);
                s8v b2 = *(const s8v*)&Bt[rB2 + ks * 32];
                acc[2] = __builtin_amdgcn_mfma_f32_16x16x32_bf16(af, b2, acc[2], 0, 0, 0);
            }
        }
        __syncthreads();
    }

    // ---- stats reduction: 32-lane groups own fixed rows ----
    #pragma unroll
    for (int p = 0; p < 5; ++p) {
        const int row = (p < 4) ? (p * 8 + gg) : (32 + gg);
        #pragma unroll
        for (int s = 0; s < 3; ++s) {
            float a = sx[p][s], c = sy[p][s];
            for (int o = 16; o > 0; o >>= 1) { a += __shfl_down(a, o, 32); c += __shfl_down(c, o, 32); }
            if ((t & 31) == 0 && row < MR) { stx[row * 3 + s] = a; sty[row * 3 + s] = c; }
        }
    }
    __syncthreads();

    // ---- derived per-row: 1/norm, dustbin scores (LayerNorm -> linear -> tanh) ----
    // (A/B tiles are dead now; C2T becomes live here.)
    {
        const float blin = BL[0];
        if (t < MR) {
            float Sx = stx[t * 3], Sxx = stx[t * 3 + 1], Sxw = stx[t * 3 + 2];
            rnx[t] = __builtin_amdgcn_rsqf(Sxx);
            float mu  = Sx * (1.0f / HD);
            float var = Sxx * (1.0f / HD) - mu * mu;
            float rsd = __builtin_amdgcn_rsqf(var + 1e-5f);
            float lin = (Sxw - mu * s_gw) * rsd + s_bw + blin;
            float e   = __builtin_amdgcn_exp2f(2.0f * LOG2E * lin);
            float th  = (e - 1.0f) / (e + 1.0f);
            C2 [t * CS + 36] = th * KC2;
            C2T[36 * CS + t] = th * KC2;
        } else if (t >= 64 && t < 64 + MR) {
            int j = t - 64;
            float Sy = sty[j * 3], Syy = sty[j * 3 + 1], Syw = sty[j * 3 + 2];
            rny[j] = __builtin_amdgcn_rsqf(Syy);
            float mu  = Sy * (1.0f / HD);
            float var = Syy * (1.0f / HD) - mu * mu;
            float rsd = __builtin_amdgcn_rsqf(var + 1e-5f);
            float lin = (Syw - mu * s_gw) * rsd + s_bw + blin;
            float e   = __builtin_amdgcn_exp2f(2.0f * LOG2E * lin);
            float th  = (e - 1.0f) / (e + 1.0f);
            C2 [36 * CS + j] = th * KC2;
            C2T[j * CS + 36] = th * KC2;
        } else if (t == 128) {
            C2 [36 * CS + 36] = -100.0f * KC2;   // ALPHA_BOTH/REG in base-2
            C2T[36 * CS + 36] = -100.0f * KC2;
        } else if (t >= 192 && t < 192 + 37) {
            int r = t - 192;                     // C2T pad cols (re-init: aliased space)
            C2T[r * CS + 37] = NEGB; C2T[r * CS + 38] = NEGB; C2T[r * CS + 39] = NEGB;
        }
    }
    __syncthreads();

    // ---- scores -> couplings (base-2) into C2 and C2T ----
    if (wv < 3) {
        #pragma unroll
        for (int tn = 0; tn < 3; ++tn) {
            #pragma unroll
            for (int r = 0; r < 4; ++r) {
                int i = wv * 16 + fq * 4 + r;   // A-operand index (x row)
                int j = tn * 16 + frow;         // B-operand index (y row)
                if (i < MR && j < MR) {
                    float v = acc[tn][r] * rnx[i] * rny[j] * KC2;
                    C2 [i * CS + j] = v;
                    C2T[j * CS + i] = v;
                }
            }
        }
    }
    __syncthreads();

    // ---- Sinkhorn: wave (b&3) -> spreads the serial phase across SIMDs ----
    if (wv == (b & 3) && ln < 37) {
        const int i = ln;
        const float lmu = (i < MR) ? -L272 : -1.0f;  // log2 marginals (mu == nu for M==N)
        const float* Cr = C2  + i * CS;
        const float* Ct = C2T + i * CS;
        for (int it = 0; it < ITERS; ++it) {
            {   // u-update: LSE over columns j of (C + v)
                f4 s[10], ma, mb;
                #pragma unroll
                for (int jj = 0; jj < 10; ++jj) {
                    f4 sv = *(const f4*)(Cr + jj * 4) + *(const f4*)(&v_l[jj * 4]);
                    s[jj] = sv;
                    if (jj == 0) ma = sv;
                    else if (jj == 1) mb = sv;
                    else if (jj & 1) mb = fmax4(mb, sv);
                    else ma = fmax4(ma, sv);
                }
                f4 mm = fmax4(ma, mb);
                float m = fmaxf(fmaxf(mm.x, mm.y), fmaxf(mm.z, mm.w));
                f4 ea = (f4){0.0f,0.0f,0.0f,0.0f}, eb = (f4){0.0f,0.0f,0.0f,0.0f};
                #pragma unroll
                for (int jj = 0; jj < 10; ++jj) {
                    f4 sv = s[jj], ev;
                    ev.x = __builtin_amdgcn_exp2f(sv.x - m);
                    ev.y = __builtin_amdgcn_exp2f(sv.y - m);
                    ev.z = __builtin_amdgcn_exp2f(sv.z - m);
                    ev.w = __builtin_amdgcn_exp2f(sv.w - m);
                    if (jj & 1) eb += ev; else ea += ev;
                }
                f4 et = ea + eb;
                float ss = (et.x + et.y) + (et.z + et.w);
                u_l[i] = lmu - (m + __builtin_amdgcn_logf(ss));
            }
            {   // v-update: LSE over rows i of (C + u) == over cols of C^T
                f4 s[10], ma, mb;
                #pragma unroll
                for (int jj = 0; jj < 10; ++jj) {
                    f4 sv = *(const f4*)(Ct + jj * 4) + *(const f4*)(&u_l[jj * 4]);
                    s[jj] = sv;
                    if (jj == 0) ma = sv;
                    else if (jj == 1) mb = sv;
                    else if (jj & 1) mb = fmax4(mb, sv);
                    else ma = fmax4(ma, sv);
                }
                f4 mm = fmax4(ma, mb);
                float m = fmaxf(fmaxf(mm.x, mm.y), fmaxf(mm.z, mm.w));
                f4 ea = (f4){0.0f,0.0f,0.0f,0.0f}, eb = (f4){0.0f,0.0f,0.0f,0.0f};
                #pragma unroll
                for (int jj = 0; jj < 10; ++jj) {
                    f4 sv = s[jj], ev;
                    ev.x = __builtin_amdgcn_exp2f(sv.x - m);
                    ev.y = __builtin_amdgcn_exp2f(sv.y - m);
                    ev.z = __builtin_amdgcn_exp2f(sv.z - m);
                    ev.w = __builtin_amdgcn_exp2f(sv.w - m);
                    if (jj & 1) eb += ev; else ea += ev;
                }
                f4 et = ea + eb;
                float ss = (et.x + et.y) + (et.z + et.w);
                v_l[i] = lmu - (m + __builtin_amdgcn_logf(ss));
            }
        }
    }
    __syncthreads();

    // ---- epilogue: Z write + total = <exp(Z), scores>/TEMP ----
    float tot = 0.0f;
    const size_t ob = (size_t)b * 1369;
    for (int e = t; e < 1369; e += 256) {
        int i = e / 37, j = e - i * 37;
        float c2v = C2[i * CS + j];
        float z2  = c2v + u_l[i] + v_l[j] + L272;   // - norm_c == + log2(72) in base-2
        OUT[ob + e] = z2 * LN2;
        if (i < MR && j < MR)
            tot += __builtin_amdgcn_exp2f(z2) * (c2v * (0.1f * LN2));  // scores = C2 * REG * ln2
    }
    for (int o = 32; o > 0; o >>= 1) tot += __shfl_down(tot, o);
    if (ln == 0) red[wv] = tot;
    __syncthreads();
    if (t == 0) OUT[(size_t)NB * 1369 + b] = (red[0] + red[1] + red[2] + red[3]) * 10.0f;  // /TEMP
}

extern "C" void kernel_launch(void* const* d_in, const int* in_sizes, int n_in,
                              void* d_out, int out_size, void* d_ws, size_t ws_size,
                              hipStream_t stream) {
    const float* X  = (const float*)d_in[0];
    const float* Y  = (const float*)d_in[1];
    const float* LG = (const float*)d_in[2];
    const float* LB = (const float*)d_in[3];
    const float* W  = (const float*)d_in[4];
    const float* BL = (const float*)d_in[5];
    const int NB = in_sizes[0] / (MR * HD);   // 2048
    hipLaunchKernelGGL(sinkhorn_kernel, dim3(NB), dim3(256), 0, stream,
                       X, Y, LG, LB, W, BL, (float*)d_out, NB);
}